// Round 5
// baseline (165.233 us; speedup 1.0000x reference)
//
#include <hip/hip_runtime.h>
#include <math.h>

// Problem dims (fixed by the reference)
#define M_COMP  8
#define DIN     1024   // input size = DK = DV
#define HDV     4096   // H * DV
#define HID     1024
#define DTOT    8192   // HID * M
#define NV_ROWS 32768  // M_COMP * HDV

// Wo rows [NT_START, DTOT) are loaded non-temporally (LLC no-allocate) so the
// first ~220 MB of weights (Wv + Wo prefix) stay Infinity-Cache-resident
// across graph replays. 3072 rows * 16 KB = 48 MB victim window.
#define NT_START 5120

typedef float f32x4 __attribute__((ext_vector_type(4)));

__device__ __forceinline__ float wave_reduce_sum(float v) {
    #pragma unroll
    for (int off = 32; off > 0; off >>= 1)
        v += __shfl_down(v, off, 64);
    return v;
}

// ---------------------------------------------------------------------------
// Kernel 1: v[row] = x[m,:]·Wv[row,:] + bv[row]. 4 consecutive rows per wave,
// x register-cached. 2048 blocks. Thread (0,0) also resets the ticket counter
// for kernel 2 (visible at k2 start via kernel-boundary ordering).
// ---------------------------------------------------------------------------
__global__ __launch_bounds__(256) void k_v4(
    const float* __restrict__ x, const float* __restrict__ Wv,
    const float* __restrict__ bv, float* __restrict__ v_out,
    unsigned* __restrict__ counter)
{
    if (blockIdx.x == 0 && threadIdx.x == 0) *counter = 0u;
    const int wave = (int)((blockIdx.x * blockDim.x + threadIdx.x) >> 6);
    const int lane = threadIdx.x & 63;
    const int row0 = wave * 4;                     // 0..NV_ROWS-4
    const int m    = row0 >> 12;                   // 4096 rows per m
    const float* __restrict__ xr = x + m * DIN;
    f32x4 xv[4];
    #pragma unroll
    for (int it = 0; it < 4; ++it)
        xv[it] = *reinterpret_cast<const f32x4*>(xr + it * 256 + lane * 4);
    const float* __restrict__ wr = Wv + (size_t)row0 * DIN;
    float acc[4] = {0.f, 0.f, 0.f, 0.f};
    #pragma unroll
    for (int r = 0; r < 4; ++r) {
        #pragma unroll
        for (int it = 0; it < 4; ++it) {
            const f32x4 w4 = *reinterpret_cast<const f32x4*>(
                wr + (size_t)r * DIN + it * 256 + lane * 4);
            acc[r] += w4.x * xv[it].x + w4.y * xv[it].y +
                      w4.z * xv[it].z + w4.w * xv[it].w;
        }
    }
    #pragma unroll
    for (int r = 0; r < 4; ++r) {
        const float s = wave_reduce_sum(acc[r]);
        if (lane == 0) v_out[row0 + r] = s + bv[row0 + r];
    }
}

// ---------------------------------------------------------------------------
// Kernel 2: per-wave partial of sum_d t[d],
//   t[d] = (v[m,:]·Wo[d,:] + bo[d] - K0[d]) * W[d]^2 * Wout[d],
// 2 consecutive d-rows per wave (32 KB contiguous). Rows >= NT_START use
// nontemporal loads. Last-finishing block (fence+ticket) does the final
// fixed-tree reduction over the 4096 partials + sigmoid -> out.
// ---------------------------------------------------------------------------
__global__ __launch_bounds__(256) void k_o2f(
    const float* __restrict__ v, const float* __restrict__ Wo,
    const float* __restrict__ bo, const float* __restrict__ K0,
    const float* __restrict__ W, const float* __restrict__ Wout,
    const float* __restrict__ bout, float* __restrict__ partials,
    unsigned* __restrict__ counter, float* __restrict__ out)
{
    const int wave = (int)((blockIdx.x * blockDim.x + threadIdx.x) >> 6);
    const int lane = threadIdx.x & 63;
    const int d0   = wave * 2;                     // 0..DTOT-2
    const int m    = d0 >> 10;                     // 1024 rows per m
    const float* __restrict__ vr = v + m * HDV;
    const float* __restrict__ wr = Wo + (size_t)d0 * HDV;
    float acc0 = 0.f, acc1 = 0.f;
    if (d0 >= NT_START) {
        #pragma unroll
        for (int it = 0; it < 16; ++it) {
            const int i = it * 256 + lane * 4;
            const f32x4 v4 = *reinterpret_cast<const f32x4*>(vr + i);
            const f32x4 a4 = __builtin_nontemporal_load(
                reinterpret_cast<const f32x4*>(wr + i));
            const f32x4 b4 = __builtin_nontemporal_load(
                reinterpret_cast<const f32x4*>(wr + HDV + i));
            acc0 += a4.x * v4.x + a4.y * v4.y + a4.z * v4.z + a4.w * v4.w;
            acc1 += b4.x * v4.x + b4.y * v4.y + b4.z * v4.z + b4.w * v4.w;
        }
    } else {
        #pragma unroll
        for (int it = 0; it < 16; ++it) {
            const int i = it * 256 + lane * 4;
            const f32x4 v4 = *reinterpret_cast<const f32x4*>(vr + i);
            const f32x4 a4 = *reinterpret_cast<const f32x4*>(wr + i);
            const f32x4 b4 = *reinterpret_cast<const f32x4*>(wr + HDV + i);
            acc0 += a4.x * v4.x + a4.y * v4.y + a4.z * v4.z + a4.w * v4.w;
            acc1 += b4.x * v4.x + b4.y * v4.y + b4.z * v4.z + b4.w * v4.w;
        }
    }
    acc0 = wave_reduce_sum(acc0);
    acc1 = wave_reduce_sum(acc1);
    if (lane == 0) {
        const float w0 = W[d0],     c0 = w0 * w0 * Wout[d0];
        const float w1 = W[d0 + 1], c1 = w1 * w1 * Wout[d0 + 1];
        partials[wave] = (acc0 + bo[d0]     - K0[d0])     * c0 +
                         (acc1 + bo[d0 + 1] - K0[d0 + 1]) * c1;
        __threadfence();                           // release this wave's partial
    }
    __syncthreads();                               // all 4 partials fenced
    __shared__ int amlast;
    if (threadIdx.x == 0) {
        const unsigned t = atomicAdd(counter, 1u); // ticket
        amlast = (t == (unsigned)(gridDim.x - 1));
    }
    __syncthreads();
    if (amlast) {
        __threadfence();                           // acquire all partials
        const int t = threadIdx.x;
        float acc = 0.f;
        #pragma unroll
        for (int k = 0; k < 4096 / 256; ++k)
            acc += partials[t + k * 256];
        acc = wave_reduce_sum(acc);
        __shared__ float s[4];
        if ((t & 63) == 0) s[t >> 6] = acc;
        __syncthreads();
        if (t == 0)
            out[0] = 1.f / (1.f + expf(-(s[0] + s[1] + s[2] + s[3] + bout[0])));
    }
}

extern "C" void kernel_launch(void* const* d_in, const int* in_sizes, int n_in,
                              void* d_out, int out_size, void* d_ws, size_t ws_size,
                              hipStream_t stream) {
    // setup_inputs order:
    // 0:x 1:Wq 2:bq 3:Wk 4:bk 5:Wv 6:bv 7:Wo 8:bo 9:K 10:W 11:Wout 12:bout
    const float* x    = (const float*)d_in[0];
    const float* Wv   = (const float*)d_in[5];
    const float* bv   = (const float*)d_in[6];
    const float* Wo   = (const float*)d_in[7];
    const float* bo   = (const float*)d_in[8];
    const float* K    = (const float*)d_in[9];   // only row 0: argmin(cumsum(>=0)) == 0
    const float* W    = (const float*)d_in[10];
    const float* Wout = (const float*)d_in[11];
    const float* bout = (const float*)d_in[12];
    float* out = (float*)d_out;

    // ws layout: v (32768 f32) | partials (4096 f32) | counter (1 u32)
    float*    v_ws = (float*)d_ws;
    float*    p_ws = v_ws + NV_ROWS;
    unsigned* cnt  = (unsigned*)(p_ws + 4096);

    // Kernel 1: 32768 rows / 4 per wave / 4 waves per block = 2048 blocks
    k_v4<<<NV_ROWS / 16, 256, 0, stream>>>(x, Wv, bv, v_ws, cnt);
    // Kernel 2: 8192 rows / 2 per wave / 4 waves per block = 1024 blocks
    k_o2f<<<DTOT / 8, 256, 0, stream>>>(v_ws, Wo, bo, K, W, Wout, bout,
                                        p_ws, cnt, out);
}

// Round 6
// 48.104 us; speedup vs baseline: 3.4349x; 3.4349x over previous
//
#include <hip/hip_runtime.h>
#include <math.h>

// Problem dims (fixed by the reference)
#define M_COMP 8
#define DIN    1024   // input size = DK = DV
#define HDV    4096   // H * DV
#define HID    1024
#define DTOT   8192   // HID * M

__device__ __forceinline__ float wave_reduce_sum(float v) {
    #pragma unroll
    for (int off = 32; off > 0; off >>= 1)
        v += __shfl_down(v, off, 64);
    return v;
}

// Kernel 1: v[m,i] = dot(x[m,:], Wv[m,i,:]) + bv[m,i]
// rows = M_COMP * HDV = 32768, one 64-lane wave per row.
// Row length DIN=1024 floats = 4 KB -> 4 iterations of float4 per lane.
__global__ __launch_bounds__(256) void k_v_matvec(
    const float* __restrict__ x, const float* __restrict__ Wv,
    const float* __restrict__ bv, float* __restrict__ v_out)
{
    const int gwave = (int)((blockIdx.x * blockDim.x + threadIdx.x) >> 6);
    const int lane  = threadIdx.x & 63;
    if (gwave >= M_COMP * HDV) return;
    const int m = gwave >> 12;                       // row / 4096
    const float* __restrict__ xr = x + m * DIN;
    const float* __restrict__ wr = Wv + (size_t)gwave * DIN;
    float acc = 0.f;
    #pragma unroll
    for (int it = 0; it < DIN / 256; ++it) {
        const int d = it * 256 + lane * 4;
        const float4 w4 = *reinterpret_cast<const float4*>(wr + d);
        const float4 x4 = *reinterpret_cast<const float4*>(xr + d);
        acc += w4.x * x4.x + w4.y * x4.y + w4.z * x4.z + w4.w * x4.w;
    }
    acc = wave_reduce_sum(acc);
    if (lane == 0) v_out[gwave] = acc + bv[gwave];
}

// Kernel 2: out[d] = dot(v[m,:], Wo[m,j,:]) + bo[d], d = m*HID + j
// then t[d] = (out[d] - K[0,d]) * W[d]^2 * Wout[d]
// rows = DTOT = 8192, one wave per row. Row length HDV=4096 floats = 16 KB.
// Note Wo[m,j,:] sits at flat offset d*HDV (contiguous).
__global__ __launch_bounds__(256) void k_out_matvec(
    const float* __restrict__ v, const float* __restrict__ Wo,
    const float* __restrict__ bo, const float* __restrict__ K0,
    const float* __restrict__ W, const float* __restrict__ Wout,
    float* __restrict__ t_out)
{
    const int d    = (int)((blockIdx.x * blockDim.x + threadIdx.x) >> 6);
    const int lane = threadIdx.x & 63;
    if (d >= DTOT) return;
    const int m = d >> 10;                           // row / HID
    const float* __restrict__ vr = v + m * HDV;
    const float* __restrict__ wr = Wo + (size_t)d * HDV;
    float acc = 0.f;
    #pragma unroll
    for (int it = 0; it < HDV / 256; ++it) {
        const int i = it * 256 + lane * 4;
        const float4 w4 = *reinterpret_cast<const float4*>(wr + i);
        const float4 v4 = *reinterpret_cast<const float4*>(vr + i);
        acc += w4.x * v4.x + w4.y * v4.y + w4.z * v4.z + w4.w * v4.w;
    }
    acc = wave_reduce_sum(acc);
    if (lane == 0) {
        const float outd = acc + bo[d];
        const float w    = W[d];
        t_out[d] = (outd - K0[d]) * w * w * Wout[d];
    }
}

// Kernel 3: scalar = sum(t) + bout; out = sigmoid(scalar).
// Single block, fixed-tree deterministic reduction.
__global__ __launch_bounds__(256) void k_final(
    const float* __restrict__ t, const float* __restrict__ bout,
    float* __restrict__ out)
{
    __shared__ float sred[4];
    const int tid = threadIdx.x;
    float acc = 0.f;
    #pragma unroll
    for (int k = 0; k < DTOT / 256; ++k)
        acc += t[tid + k * 256];
    acc = wave_reduce_sum(acc);
    if ((tid & 63) == 0) sred[tid >> 6] = acc;
    __syncthreads();
    if (tid == 0) {
        const float total = sred[0] + sred[1] + sred[2] + sred[3] + bout[0];
        out[0] = 1.f / (1.f + expf(-total));
    }
}

extern "C" void kernel_launch(void* const* d_in, const int* in_sizes, int n_in,
                              void* d_out, int out_size, void* d_ws, size_t ws_size,
                              hipStream_t stream) {
    // setup_inputs order:
    // 0:x 1:Wq 2:bq 3:Wk 4:bk 5:Wv 6:bv 7:Wo 8:bo 9:K 10:W 11:Wout 12:bout
    const float* x    = (const float*)d_in[0];
    const float* Wv   = (const float*)d_in[5];
    const float* bv   = (const float*)d_in[6];
    const float* Wo   = (const float*)d_in[7];
    const float* bo   = (const float*)d_in[8];
    const float* K    = (const float*)d_in[9];   // only row 0 is ever needed
    const float* W    = (const float*)d_in[10];
    const float* Wout = (const float*)d_in[11];
    const float* bout = (const float*)d_in[12];
    float* out = (float*)d_out;

    // workspace layout: v (32768 f32) | t (8192 f32)
    float* v_ws = (float*)d_ws;
    float* t_ws = v_ws + (M_COMP * HDV);

    // Kernel 1: 32768 rows, 4 waves/block -> 8192 blocks
    k_v_matvec<<<(M_COMP * HDV) / 4, 256, 0, stream>>>(x, Wv, bv, v_ws);
    // Kernel 2: 8192 rows, 4 waves/block -> 2048 blocks
    k_out_matvec<<<DTOT / 4, 256, 0, stream>>>(v_ws, Wo, bo, K, W, Wout, t_ws);
    // Kernel 3: single block
    k_final<<<1, 256, 0, stream>>>(t_ws, bout, out);
}